// Round 6
// baseline (365.880 us; speedup 1.0000x reference)
//
#include <hip/hip_runtime.h>
#include <hip/hip_fp16.h>

#define IN_FEAT 128
#define HEADS 8
#define OUT_FEAT 16
#define HF 128       // HEADS*OUT_FEAT
#define BSHIFT 7     // bucket = dst >> 7  (128 nodes/bucket)
#define BNODES 128
#define NBMAX 512
#define CHUNK 8192   // edges per bucket_scatter block

// ---------------- K1: h = feat @ W_fc (fp16 out) and post[n][k][h] (fp32) ----
__global__ __launch_bounds__(256) void gemm_post_kernel(
    const float* __restrict__ feat, const float* __restrict__ W_fc,
    const float* __restrict__ W_post, const float* __restrict__ b_post,
    __half* __restrict__ hbuf, float* __restrict__ post, int N)
{
    __shared__ float4 lds4[32 * 32];          // 32 nodes x 128 feats (16 KB)
    float* lds = (float*)lds4;
    const int tid = threadIdx.x;
    const int node_base = blockIdx.x * 32;

    const float4* f4 = (const float4*)feat;
    for (int i = tid; i < 32 * 32; i += 256) {
        int n = i >> 5, k4 = i & 31;
        int gn = node_base + n;
        float4 v = make_float4(0.f, 0.f, 0.f, 0.f);
        if (gn < N) v = f4[gn * 32 + k4];
        lds4[i] = v;
    }
    __syncthreads();

    const int cg = tid & 31, ng = tid >> 5;
    const int n0 = ng * 4;
    float acc[4][4];
#pragma unroll
    for (int i = 0; i < 4; i++) acc[i][0] = acc[i][1] = acc[i][2] = acc[i][3] = 0.f;

    const float4* W4 = (const float4*)W_fc;
#pragma unroll 4
    for (int k = 0; k < 128; ++k) {
        float4 w = W4[k * 32 + cg];
#pragma unroll
        for (int i = 0; i < 4; i++) {
            float f = lds[(n0 + i) * 128 + k];
            acc[i][0] += f * w.x; acc[i][1] += f * w.y;
            acc[i][2] += f * w.z; acc[i][3] += f * w.w;
        }
    }
    __half2* hb2 = (__half2*)hbuf;
#pragma unroll
    for (int i = 0; i < 4; i++) {
        int gn = node_base + n0 + i;
        if (gn < N) {
            union { uint2 u; __half2 h[2]; } pk;
            pk.h[0] = __floats2half2_rn(acc[i][0], acc[i][1]);
            pk.h[1] = __floats2half2_rn(acc[i][2], acc[i][3]);
            *(uint2*)&hb2[gn * 64 + cg * 2] = pk.u;
        }
    }
    __syncthreads();
#pragma unroll
    for (int i = 0; i < 4; i++)
        lds4[(n0 + i) * 32 + cg] = make_float4(acc[i][0], acc[i][1], acc[i][2], acc[i][3]);
    __syncthreads();

    {
        int n = tid >> 3, h = tid & 7;
        float p0 = b_post[0], p1 = b_post[1], p2 = b_post[2], p3 = b_post[3];
#pragma unroll
        for (int f = 0; f < 16; ++f) {
            float v = lds[n * 128 + h * 16 + f];
            p0 += v * W_post[f * 4 + 0];
            p1 += v * W_post[f * 4 + 1];
            p2 += v * W_post[f * 4 + 2];
            p3 += v * W_post[f * 4 + 3];
        }
        int gn = node_base + n;
        if (gn < N) {
            // layout post[n][k][h], k: 0=loc_l 1=loc_r 2=lsl 3=lsr
            post[gn * 32 + 0 * 8 + h] = p0;
            post[gn * 32 + 1 * 8 + h] = p1;
            post[gn * 32 + 2 * 8 + h] = p2;
            post[gn * 32 + 3 * 8 + h] = p3;
        }
    }
}

// ---------------- K2: bucket histogram (bucket = dst>>7) ----------------
__global__ __launch_bounds__(256) void bucket_hist_kernel(
    const int* __restrict__ dst, int* __restrict__ bucket_tot, int E, int nb)
{
    __shared__ int cnt[NBMAX];
    const int tid = threadIdx.x;
    for (int i = tid; i < nb; i += 256) cnt[i] = 0;
    __syncthreads();
    const int stride = gridDim.x * 256;
    for (int g = blockIdx.x * 256 + tid; g < E; g += stride)
        atomicAdd(&cnt[dst[g] >> BSHIFT], 1);
    __syncthreads();
    for (int i = tid; i < nb; i += 256) {
        int c = cnt[i];
        if (c) atomicAdd(&bucket_tot[i], c);
    }
}

// ---------------- K3: scan bucket totals -> base, cursor ----------------
__global__ __launch_bounds__(256) void bucket_scan_kernel(
    const int* __restrict__ bucket_tot, int* __restrict__ bucket_base,
    int* __restrict__ bucket_cursor, int nb, int E)
{
    __shared__ int sd[256];
    const int tid = threadIdx.x;
    int v[2]; int s = 0;
#pragma unroll
    for (int k = 0; k < 2; ++k) {
        int i = tid * 2 + k;
        v[k] = (i < nb) ? bucket_tot[i] : 0;
        s += v[k];
    }
    sd[tid] = s;
    __syncthreads();
    for (int off = 1; off < 256; off <<= 1) {
        int t = (tid >= off) ? sd[tid - off] : 0;
        __syncthreads();
        sd[tid] += t;
        __syncthreads();
    }
    int excl = sd[tid] - s;
#pragma unroll
    for (int k = 0; k < 2; ++k) {
        int i = tid * 2 + k;
        if (i < nb) { bucket_base[i] = excl; bucket_cursor[i] = excl; }
        excl += v[k];
    }
    if (tid == 0) bucket_base[nb] = E;
}

// ---------------- K4: bin edges + eps payload into bucket regions ----------
// recPair = src<<16 | dst (both < 65536), recEps = eps fp16x8 (coalesced read
// of eps since each block owns a contiguous edge range).
__global__ __launch_bounds__(256) void bucket_scatter_kernel(
    const int* __restrict__ src, const int* __restrict__ dst,
    const float* __restrict__ eps, int* __restrict__ bucket_cursor,
    unsigned* __restrict__ recPair, float4* __restrict__ recEps, int E, int nb)
{
    __shared__ int cnt[NBMAX];
    __shared__ int base[NBMAX];
    const int tid = threadIdx.x;
    for (int i = tid; i < nb; i += 256) cnt[i] = 0;
    __syncthreads();
    const int e0 = blockIdx.x * CHUNK;
    const int e1 = min(e0 + CHUNK, E);
    for (int e = e0 + tid; e < e1; e += 256)
        atomicAdd(&cnt[dst[e] >> BSHIFT], 1);
    __syncthreads();
    for (int i = tid; i < nb; i += 256) {
        int c = cnt[i];
        base[i] = c ? atomicAdd(&bucket_cursor[i], c) : 0;
        cnt[i] = 0;   // reuse as local cursor
    }
    __syncthreads();
    const float4* eps4 = (const float4*)eps;
    for (int e = e0 + tid; e < e1; e += 256) {
        int d = dst[e];
        int b = d >> BSHIFT;
        int slot = base[b] + atomicAdd(&cnt[b], 1);
        recPair[slot] = ((unsigned)src[e] << 16) | (unsigned)d;
        float4 x0 = eps4[(size_t)e * 2], x1 = eps4[(size_t)e * 2 + 1];
        union { float4 f4; __half2 h2[4]; } pk;
        pk.h2[0] = __floats2half2_rn(x0.x, x0.y);
        pk.h2[1] = __floats2half2_rn(x0.z, x0.w);
        pk.h2[2] = __floats2half2_rn(x1.x, x1.y);
        pk.h2[3] = __floats2half2_rn(x1.z, x1.w);
        recEps[slot] = pk.f4;
    }
}

// ---------------- K5: per-bucket CSR build (pure streaming permute) --------
__global__ __launch_bounds__(256) void bucket_csr_kernel(
    const unsigned* __restrict__ recPair, const float4* __restrict__ recEps,
    const int* __restrict__ bucket_base, int* __restrict__ offsets,
    unsigned* __restrict__ csrPair, float4* __restrict__ csrEps, int N, int E)
{
    __shared__ int ncnt[BNODES];
    __shared__ int snc[BNODES];
    const int b = blockIdx.x, tid = threadIdx.x;
    const int node_lo = b << BSHIFT;
    const int rlo = bucket_base[b], rhi = bucket_base[b + 1];
    const int gn = node_lo + tid;

    if (tid < BNODES) ncnt[tid] = 0;
    __syncthreads();
    for (int r = rlo + tid; r < rhi; r += 256)
        atomicAdd(&ncnt[recPair[r] & (BNODES - 1u)], 1);
    __syncthreads();
    if (tid < BNODES) snc[tid] = ncnt[tid];
    __syncthreads();
    for (int off = 1; off < BNODES; off <<= 1) {
        int t = (tid < BNODES && tid >= off) ? snc[tid - off] : 0;
        __syncthreads();
        if (tid < BNODES) snc[tid] += t;
        __syncthreads();
    }
    int excl = (tid < BNODES) ? snc[tid] - ncnt[tid] : 0;
    if (tid < BNODES && gn < N) offsets[gn] = rlo + excl;
    if (b == 0 && tid == 0) offsets[N] = E;
    __syncthreads();
    if (tid < BNODES) ncnt[tid] = excl;   // relative cursor
    __syncthreads();

    for (int r = rlo + tid; r < rhi; r += 256) {
        unsigned pr = recPair[r];
        int dl = (int)(pr & (BNODES - 1u));
        int slot = rlo + atomicAdd(&ncnt[dl], 1);
        csrPair[slot] = pr;
        csrEps[slot] = recEps[r];
    }
}

// ---------------- K6: scores in CSR slot order (in-place eps -> ex) --------
__global__ __launch_bounds__(256) void score_csr_kernel(
    const unsigned* __restrict__ csrPair, const float* __restrict__ post,
    float4* __restrict__ csrEx, int E)
{
    int slot = blockIdx.x * 256 + threadIdx.x;
    if (slot >= E) return;
    unsigned pr = csrPair[slot];
    int s = (int)(pr >> 16), d = (int)(pr & 0xFFFFu);
    const float4* p4 = (const float4*)post;   // post row = 8 float4
    float4 ll0 = p4[s * 8 + 0], ll1 = p4[s * 8 + 1];   // loc_l[0..7]
    float4 sl0 = p4[s * 8 + 4], sl1 = p4[s * 8 + 5];   // lsl[0..7]
    float4 lr0 = p4[d * 8 + 2], lr1 = p4[d * 8 + 3];   // loc_r (deg-run L1 hits)
    float4 sr0 = p4[d * 8 + 6], sr1 = p4[d * 8 + 7];   // lsr
    union { float4 f4; __half2 h2[4]; } ue;
    ue.f4 = csrEx[slot];

    float ll[8] = {ll0.x, ll0.y, ll0.z, ll0.w, ll1.x, ll1.y, ll1.z, ll1.w};
    float sl[8] = {sl0.x, sl0.y, sl0.z, sl0.w, sl1.x, sl1.y, sl1.z, sl1.w};
    float lr[8] = {lr0.x, lr0.y, lr0.z, lr0.w, lr1.x, lr1.y, lr1.z, lr1.w};
    float sr[8] = {sr0.x, sr0.y, sr0.z, sr0.w, sr1.x, sr1.y, sr1.z, sr1.w};
    float ep[8];
#pragma unroll
    for (int k = 0; k < 4; ++k) {
        float2 f = __half22float2(ue.h2[k]);
        ep[2 * k] = f.x; ep[2 * k + 1] = f.y;
    }
    union { float4 f4; __half2 h2[4]; } pk;
#pragma unroll
    for (int h = 0; h < 4; ++h) {
        float ev0 = (ll[2*h]   + lr[2*h])   + __expf(sl[2*h]   + sr[2*h])   * ep[2*h];
        float ev1 = (ll[2*h+1] + lr[2*h+1]) + __expf(sl[2*h+1] + sr[2*h+1]) * ep[2*h+1];
        pk.h2[h] = __floats2half2_rn(__expf(ev0), __expf(ev1));
    }
    csrEx[slot] = pk.f4;
}

// ---------------- K7: aggregation (unrolled gather loop) ----------------
// block = 128 = 2 waves, one dst node. lane -> (h = lane>>3, fp = lane&7);
// wave w handles staged edges j = w, w+2, ... with 4-edge unroll for MLP.
__global__ __launch_bounds__(128) void agg_kernel(
    const unsigned* __restrict__ csrPair, const int* __restrict__ offsets,
    const float4* __restrict__ csrEx, const __half* __restrict__ hbuf,
    const float* __restrict__ bias, float* __restrict__ out)
{
    __shared__ int    s_src[32];
    __shared__ float  s_a[32 * 9];      // stride 9: conflict-light
    __shared__ float2 r_acc[64];
    __shared__ float  r_dsum[64];

    const int d = blockIdx.x;
    const int tid = threadIdx.x;
    const int wave = tid >> 6, lane = tid & 63;
    const int h = lane >> 3, fp = lane & 7;
    const int start = offsets[d];
    const int deg = offsets[d + 1] - start;

    float2 acc = make_float2(0.f, 0.f);
    float dsum = 0.f;

    for (int c = 0; c < deg; c += 32) {
        int jc = min(32, deg - c);
        if (tid < jc) {
            s_src[tid] = (int)(csrPair[start + c + tid] >> 16);
            union { float4 f4; __half2 h2[4]; } u;
            u.f4 = csrEx[start + c + tid];   // coalesced
#pragma unroll
            for (int k = 0; k < 4; ++k) {
                float2 f = __half22float2(u.h2[k]);
                s_a[tid * 9 + 2 * k]     = f.x;
                s_a[tid * 9 + 2 * k + 1] = f.y;
            }
        }
        __syncthreads();
        int j = wave;
        for (; j + 6 < jc; j += 8) {
            int s0 = s_src[j], s1 = s_src[j + 2], s2 = s_src[j + 4], s3 = s_src[j + 6];
            float a0 = s_a[j * 9 + h],       a1 = s_a[(j + 2) * 9 + h];
            float a2 = s_a[(j + 4) * 9 + h], a3 = s_a[(j + 6) * 9 + h];
            float2 v0 = __half22float2(((const __half2*)(hbuf + (size_t)s0 * 128))[lane]);
            float2 v1 = __half22float2(((const __half2*)(hbuf + (size_t)s1 * 128))[lane]);
            float2 v2 = __half22float2(((const __half2*)(hbuf + (size_t)s2 * 128))[lane]);
            float2 v3 = __half22float2(((const __half2*)(hbuf + (size_t)s3 * 128))[lane]);
            acc.x += a0 * v0.x; acc.y += a0 * v0.y;
            acc.x += a1 * v1.x; acc.y += a1 * v1.y;
            acc.x += a2 * v2.x; acc.y += a2 * v2.y;
            acc.x += a3 * v3.x; acc.y += a3 * v3.y;
            dsum += a0 + a1 + a2 + a3;
        }
        for (; j < jc; j += 2) {
            float a = s_a[j * 9 + h];
            float2 hv = __half22float2(((const __half2*)(hbuf + (size_t)s_src[j] * 128))[lane]);
            acc.x += a * hv.x;
            acc.y += a * hv.y;
            dsum  += a;
        }
        __syncthreads();
    }

    if (wave == 0) { r_acc[lane] = acc; r_dsum[lane] = dsum; }
    __syncthreads();
    if (wave == 1) {
        r_acc[lane].x += acc.x;
        r_acc[lane].y += acc.y;
        r_dsum[lane]  += dsum;
    }
    __syncthreads();
    if (wave == 0) {
        float2 A = r_acc[lane];
        float ds = r_dsum[lane];
        float inv = (ds > 0.f) ? 1.f / ds : 0.f;
        float2 o;
        o.x = A.x * inv + bias[h * 16 + 2 * fp];
        o.y = A.y * inv + bias[h * 16 + 2 * fp + 1];
        ((float2*)out)[(size_t)d * 64 + lane] = o;
    }
}

extern "C" void kernel_launch(void* const* d_in, const int* in_sizes, int n_in,
                              void* d_out, int out_size, void* d_ws, size_t ws_size,
                              hipStream_t stream)
{
    const float* feat   = (const float*)d_in[0];
    const int*   src    = (const int*)d_in[1];
    const int*   dst    = (const int*)d_in[2];
    const float* eps    = (const float*)d_in[3];
    const float* W_fc   = (const float*)d_in[4];
    const float* W_post = (const float*)d_in[5];
    const float* b_post = (const float*)d_in[6];
    const float* bias   = (const float*)d_in[7];
    float* out = (float*)d_out;

    const int N = in_sizes[0] / IN_FEAT;         // 50000
    const int E = in_sizes[1];                   // 1600000
    const int nb = (N + BNODES - 1) >> BSHIFT;   // 391 buckets

    // workspace layout (256B-aligned segments), total ~71.5 MB
    char* p = (char*)d_ws;
    auto alloc = [&](size_t bytes) {
        char* r = p;
        p += (bytes + 255) & ~size_t(255);
        return r;
    };
    __half*   hbuf    = (__half*)alloc((size_t)N * HF * 2);     // 12.8 MB fp16
    float*    post    = (float*)alloc((size_t)N * 32 * 4);      // 6.4 MB
    int*      offsets = (int*)alloc((size_t)(N + 1) * 4);
    int*      bucket_tot    = (int*)alloc((size_t)(NBMAX + 1) * 4);
    int*      bucket_base   = (int*)alloc((size_t)(NBMAX + 1) * 4);
    int*      bucket_cursor = (int*)alloc((size_t)(NBMAX + 1) * 4);
    unsigned* recPair = (unsigned*)alloc((size_t)E * 4);        // 6.4 MB
    float4*   recEps  = (float4*)alloc((size_t)E * 16);         // 25.6 MB
    unsigned* csrPair = (unsigned*)alloc((size_t)E * 4);        // 6.4 MB
    float4*   csrEx   = (float4*)alloc((size_t)E * 16);         // 25.6 MB

    hipMemsetAsync(bucket_tot, 0, (size_t)nb * 4, stream);

    gemm_post_kernel<<<(N + 31) / 32, 256, 0, stream>>>(feat, W_fc, W_post, b_post,
                                                        hbuf, post, N);
    bucket_hist_kernel<<<512, 256, 0, stream>>>(dst, bucket_tot, E, nb);
    bucket_scan_kernel<<<1, 256, 0, stream>>>(bucket_tot, bucket_base,
                                              bucket_cursor, nb, E);
    bucket_scatter_kernel<<<(E + CHUNK - 1) / CHUNK, 256, 0, stream>>>(
        src, dst, eps, bucket_cursor, recPair, recEps, E, nb);
    bucket_csr_kernel<<<nb, 256, 0, stream>>>(recPair, recEps, bucket_base,
                                              offsets, csrPair, csrEx, N, E);
    score_csr_kernel<<<(E + 255) / 256, 256, 0, stream>>>(csrPair, post, csrEx, E);
    agg_kernel<<<N, 128, 0, stream>>>(csrPair, offsets, csrEx, hbuf, bias, out);
}